// Round 13
// baseline (210.513 us; speedup 1.0000x reference)
//
#include <hip/hip_runtime.h>
#include <cstdint>
#include <cstddef>

// ---- problem constants ----
#define SEQ   920
#define DM    1536
#define DH    384
#define NHD   4
#define NB    4
#define NBH   16          // NB*NHD
#define MTOK  3680        // NB*SEQ
#define NREL  1839        // 2*920-1

typedef short          bf16x8 __attribute__((ext_vector_type(8)));
typedef float          f32x4  __attribute__((ext_vector_type(4)));
typedef unsigned short u16x4  __attribute__((ext_vector_type(4)));
typedef unsigned short u16x8  __attribute__((ext_vector_type(8)));

__device__ __forceinline__ unsigned short f2bf(float f){
  union{float f; unsigned u;} v; v.f = f;
  unsigned r = v.u + 0x7FFFu + ((v.u >> 16) & 1u);
  return (unsigned short)(r >> 16);
}
__device__ __forceinline__ float bf2f(unsigned short h){
  union{unsigned u; float f;} v; v.u = ((unsigned)h) << 16;
  return v.f;
}
__device__ __forceinline__ f32x4 mfma_bf16(bf16x8 a, bf16x8 b, f32x4 c){
  return __builtin_amdgcn_mfma_f32_16x16x32_bf16(a, b, c, 0, 0, 0);
}
__device__ __forceinline__ void gload_lds16(const void* g, void* l){
  __builtin_amdgcn_global_load_lds((const __attribute__((address_space(1))) void*)g,
                                   (__attribute__((address_space(3))) void*)l, 16, 0, 0);
}

// ---- unified prep: weight transpose+convert (blocks 0..6911), X conv (..8959), E conv (..9649) ----
__global__ __launch_bounds__(256) void k_prep(const float* __restrict__ X,
                                              const float* __restrict__ de,
                                              const float* __restrict__ qw,
                                              const float* __restrict__ kw,
                                              const float* __restrict__ vw,
                                              unsigned short* __restrict__ Xb,
                                              unsigned short* __restrict__ Eb,
                                              unsigned short* __restrict__ Wt){
  __shared__ float t[32][33];
  int bid = blockIdx.x;
  if(bid < 6912){
    int z = bid / 2304, rem = bid % 2304;
    int k0 = (rem % 48) * 32, n0 = (rem / 48) * 32;
    const float* w = z == 0 ? qw : (z == 1 ? kw : vw);
    int tx = threadIdx.x & 31, ty = threadIdx.x >> 5;    // (32,8)
    #pragma unroll
    for(int j = 0; j < 4; j++)
      t[ty*4+j][tx] = w[(size_t)(k0 + ty*4 + j) * DM + n0 + tx];
    __syncthreads();
    #pragma unroll
    for(int j = 0; j < 4; j++)
      Wt[(size_t)(z*DM + n0 + ty*4 + j) * DM + k0 + tx] = f2bf(t[tx][ty*4+j]);
  } else if(bid < 6912 + 2048){
    int i = ((bid - 6912) * 256 + threadIdx.x) * 4;
    const int n = MTOK*DM, stride = 2048 * 256 * 4;
    for(; i + 3 < n; i += stride){
      f32x4 v = *(const f32x4*)(X + i);
      u16x4 o; o.x = f2bf(v.x); o.y = f2bf(v.y); o.z = f2bf(v.z); o.w = f2bf(v.w);
      *(u16x4*)(Xb + i) = o;
    }
  } else {
    int i = ((bid - 6912 - 2048) * 256 + threadIdx.x) * 4;
    if(i + 3 < NREL*DH){
      f32x4 v = *(const f32x4*)(de + i);
      u16x4 o; o.x = f2bf(v.x); o.y = f2bf(v.y); o.z = f2bf(v.z); o.w = f2bf(v.w);
      *(u16x4*)(Eb + i) = o;
    }
  }
}

// ====== 384x192 tile, BK=64, 8 waves (4M x 2N, wave 96x96), dbuf-2 (144KB) — v3 ======
// Counted-vmcnt schedule, NEVER drains to 0 in steady state (T4). Per iter:
//   P1: read own-A (12 ds_read_b128)      | stage A(t+1) (6 loads)
//   P2: vmcnt(6)+bar [B(t) landed]        | read b0(6) | stage B(t+1) (3) | 36 MFMA (kk0)
//   P3: read b1(6)                        | 36 MFMA (kk1)
//   end: vmcnt(3)+bar [A(t+1) landed; B(t+1) stays in flight]
// Issue order per iter: A(t+1)[6], B(t+1)[3]. Steady outstanding at P2 = B(t)3+A(t+1)6=9 ->
// vmcnt(6) lands B(t); at end = A(t+1)6+B(t+1)3=9 -> vmcnt(3) lands A(t+1).
// Slot-reuse safety: A(t+1)->slot sn, whose A was last read in P1(t-1); two barriers
// (P2(t-1), end(t-1)) separate those reads from this write. Same for B (read P2/P3(t-1)).
// Cross-wave landing: all waves issue identical load sequences; barrier after each counted
// wait makes the landed prefix collective.
template<class Epi>
__device__ __forceinline__ void gemm384(const unsigned short* __restrict__ A, int lda, int Amax,
                                        const unsigned short* __restrict__ B, int ldb, int Bmax,
                                        int K, int m0, int n0, Epi epi){
  __shared__ char lds[147456];                 // A dbuf 2x48KB @0, B dbuf 2x24KB @98304
  char* ldsA = lds;
  char* ldsB = lds + 98304;
  const int tid = threadIdx.x;
  const int w = tid >> 6, l = tid & 63;
  const int lg = l >> 4, lo = l & 15;
  const int wm = w >> 1, wn = w & 1;           // wave grid 4(M) x 2(N)

  const int gcol = ((tid & 7) ^ ((tid >> 3) & 7)) * 16;   // pre-swizzled column slot
  const char* gA[6]; const char* gB[3];
  #pragma unroll
  for(int u = 0; u < 6; u++){
    int ar = m0 + u*64 + (tid >> 3); ar = ar < Amax ? ar : Amax - 1;
    gA[u] = (const char*)A + (size_t)ar*lda*2 + gcol;
  }
  #pragma unroll
  for(int v = 0; v < 3; v++){
    int br = n0 + v*64 + (tid >> 3); br = br < Bmax ? br : Bmax - 1;
    gB[v] = (const char*)B + (size_t)br*ldb*2 + gcol;
  }
  auto stageA = [&](int kt, int s){
    size_t koff = (size_t)kt * 128;
    #pragma unroll
    for(int u = 0; u < 6; u++)
      gload_lds16(gA[u] + koff, ldsA + s*49152 + u*8192 + tid*16);
  };
  auto stageB = [&](int kt, int s){
    size_t koff = (size_t)kt * 128;
    #pragma unroll
    for(int v = 0; v < 3; v++)
      gload_lds16(gB[v] + koff, ldsB + s*24576 + v*8192 + tid*16);
  };

  f32x4 acc[6][6] = {};
  const int sw = (lo & 7) << 4;
  const int nk = K >> 6;

  // prologue: stage tile 0 (order A then B); land A(0); B(0) stays in flight
  stageA(0, 0);
  stageB(0, 0);
  asm volatile("s_waitcnt vmcnt(3)" ::: "memory");
  __builtin_amdgcn_s_barrier();

  for(int t = 0; t < nk; t++){
    const int s = t & 1, sn = s ^ 1;
    const bool pf = (t + 1 < nk);
    const char* Ab = ldsA + s*49152;
    const char* Bb = ldsB + s*24576;
    bf16x8 a0[6], a1[6], b0[6], b1[6];

    // ---- P1: read own A (landed via end-of-prev-iter wait) | stage A(t+1) ----
    #pragma unroll
    for(int fi = 0; fi < 6; fi++){
      a0[fi] = *(const bf16x8*)(Ab + (wm*96 + fi*16 + lo)*128 + ((lg*16) ^ sw));
      a1[fi] = *(const bf16x8*)(Ab + (wm*96 + fi*16 + lo)*128 + ((64 + lg*16) ^ sw));
    }
    if(pf) stageA(t + 1, sn);

    // ---- P2: land B(t) | read b0 | stage B(t+1) | MFMA kk0 ----
    if(pf){ asm volatile("s_waitcnt vmcnt(6)" ::: "memory"); }
    else  { asm volatile("s_waitcnt vmcnt(0)" ::: "memory"); }
    __builtin_amdgcn_s_barrier();
    #pragma unroll
    for(int fj = 0; fj < 6; fj++)
      b0[fj] = *(const bf16x8*)(Bb + (wn*96 + fj*16 + lo)*128 + ((lg*16) ^ sw));
    if(pf) stageB(t + 1, sn);
    __builtin_amdgcn_s_setprio(1);
    #pragma unroll
    for(int fi = 0; fi < 6; fi++)
      #pragma unroll
      for(int fj = 0; fj < 6; fj++)
        acc[fi][fj] = mfma_bf16(a0[fi], b0[fj], acc[fi][fj]);
    __builtin_amdgcn_s_setprio(0);

    // ---- P3: read b1 | MFMA kk1 ----
    #pragma unroll
    for(int fj = 0; fj < 6; fj++)
      b1[fj] = *(const bf16x8*)(Bb + (wn*96 + fj*16 + lo)*128 + ((64 + lg*16) ^ sw));
    __builtin_amdgcn_s_setprio(1);
    #pragma unroll
    for(int fi = 0; fi < 6; fi++)
      #pragma unroll
      for(int fj = 0; fj < 6; fj++)
        acc[fi][fj] = mfma_bf16(a1[fi], b1[fj], acc[fi][fj]);
    __builtin_amdgcn_s_setprio(0);

    // ---- end: land A(t+1); B(t+1) stays in flight ----
    if(pf){
      asm volatile("s_waitcnt vmcnt(3)" ::: "memory");
      __builtin_amdgcn_s_barrier();
    }
  }

  #pragma unroll
  for(int fi = 0; fi < 6; fi++)
    #pragma unroll
    for(int fj = 0; fj < 6; fj++){
      int m = m0 + wm*96 + fi*16 + lg*4;
      int n = n0 + wn*96 + fj*16 + lo;
      epi(m, n, acc[fi][fj]);
    }
}

// ====== 192x192 tile, BK=64, 8-wave, ring-3, counted-vmcnt, 3-PHASE GEMM (round-6, proven) ======
template<class Epi>
__device__ __forceinline__ void gemm192(const unsigned short* __restrict__ A, int lda, int Amax,
                                        const unsigned short* __restrict__ B, int ldb, int Bmax,
                                        int K, int m0, int n0, Epi epi){
  __shared__ unsigned short As[3*192*64];
  __shared__ unsigned short Bs[3*192*64];
  const int tid = threadIdx.x;
  const int w = tid >> 6, l = tid & 63;
  const int lg = l >> 4, lo = l & 15;
  const int wm = w >> 2, wn = w & 3;

  const char* ga[3]; const char* gb[3];
  #pragma unroll
  for(int r = 0; r < 3; r++){
    int row = r*64 + (tid >> 3);
    int gslot = (tid & 7) ^ (row & 7);
    int ar = m0 + row; ar = ar < Amax ? ar : Amax - 1;
    ga[r] = (const char*)A + (size_t)ar*lda*2 + gslot*16;
    int br = n0 + row; br = br < Bmax ? br : Bmax - 1;
    gb[r] = (const char*)B + (size_t)br*ldb*2 + gslot*16;
  }
  const int ldst = tid * 16;

  auto stage_pair = [&](int kt, int slot, int r){
    size_t koff = (size_t)kt * 128;
    gload_lds16(ga[r] + koff, (char*)As + slot*24576 + r*8192 + ldst);
    gload_lds16(gb[r] + koff, (char*)Bs + slot*24576 + r*8192 + ldst);
  };

  f32x4 acc[6][3] = {};
  const int sw = (lo & 7) << 4;
  const int nk = (2*K + 127) >> 7;
  const int tb = 2*K - (nk - 1)*128;
  const bool keep0 = (lg*16) < tb;
  const bool keep1 = (64 + lg*16) < tb;

  #pragma unroll
  for(int r = 0; r < 3; r++) stage_pair(0, 0, r);
  #pragma unroll
  for(int r = 0; r < 3; r++) stage_pair(1, 1, r);
  asm volatile("s_waitcnt vmcnt(6)" ::: "memory");
  __builtin_amdgcn_s_barrier();

  int st = 0;
  for(int t = 0; t < nk; t++){
    const bool last = (t == nk - 1);
    const bool pf = (t + 2 < nk);
    const int s2 = st + 2 >= 3 ? st - 1 : st + 2;
    const char* Ab = (const char*)As + st*24576;
    const char* Bb = (const char*)Bs + st*24576;

    bf16x8 bfr[3][2], afr[2][2];

    #pragma unroll
    for(int fj = 0; fj < 3; fj++){
      int row = wn*48 + fj*16 + lo;
      #pragma unroll
      for(int kk = 0; kk < 2; kk++)
        bfr[fj][kk] = *(const bf16x8*)(Bb + row*128 + ((kk*64 + lg*16) ^ sw));
    }
    #pragma unroll
    for(int fi = 0; fi < 2; fi++){
      int row = wm*96 + fi*16 + lo;
      #pragma unroll
      for(int kk = 0; kk < 2; kk++)
        afr[fi][kk] = *(const bf16x8*)(Ab + row*128 + ((kk*64 + lg*16) ^ sw));
    }
    if(pf) stage_pair(t + 2, s2, 0);
    if(last){
      #pragma unroll
      for(int fi = 0; fi < 2; fi++){
        if(!keep0) afr[fi][0] = bf16x8{};
        if(!keep1) afr[fi][1] = bf16x8{};
      }
    }
    __builtin_amdgcn_s_barrier();
    asm volatile("s_waitcnt lgkmcnt(0)" ::: "memory");
    __builtin_amdgcn_s_setprio(1);
    #pragma unroll
    for(int kk = 0; kk < 2; kk++)
      #pragma unroll
      for(int fi = 0; fi < 2; fi++)
        #pragma unroll
        for(int fj = 0; fj < 3; fj++)
          acc[fi][fj] = mfma_bf16(afr[fi][kk], bfr[fj][kk], acc[fi][fj]);
    __builtin_amdgcn_s_setprio(0);
    __builtin_amdgcn_s_barrier();

    #pragma unroll
    for(int fi = 0; fi < 2; fi++){
      int row = wm*96 + (fi + 2)*16 + lo;
      #pragma unroll
      for(int kk = 0; kk < 2; kk++)
        afr[fi][kk] = *(const bf16x8*)(Ab + row*128 + ((kk*64 + lg*16) ^ sw));
    }
    if(pf) stage_pair(t + 2, s2, 1);
    if(last){
      #pragma unroll
      for(int fi = 0; fi < 2; fi++){
        if(!keep0) afr[fi][0] = bf16x8{};
        if(!keep1) afr[fi][1] = bf16x8{};
      }
    }
    __builtin_amdgcn_s_barrier();
    asm volatile("s_waitcnt lgkmcnt(0)" ::: "memory");
    __builtin_amdgcn_s_setprio(1);
    #pragma unroll
    for(int kk = 0; kk < 2; kk++)
      #pragma unroll
      for(int fi = 0; fi < 2; fi++)
        #pragma unroll
        for(int fj = 0; fj < 3; fj++)
          acc[fi + 2][fj] = mfma_bf16(afr[fi][kk], bfr[fj][kk], acc[fi + 2][fj]);
    __builtin_amdgcn_s_setprio(0);
    __builtin_amdgcn_s_barrier();

    #pragma unroll
    for(int fi = 0; fi < 2; fi++){
      int row = wm*96 + (fi + 4)*16 + lo;
      #pragma unroll
      for(int kk = 0; kk < 2; kk++)
        afr[fi][kk] = *(const bf16x8*)(Ab + row*128 + ((kk*64 + lg*16) ^ sw));
    }
    if(pf){
      stage_pair(t + 2, s2, 2);
      asm volatile("s_waitcnt vmcnt(6)" ::: "memory");
    } else if(t + 1 < nk){
      asm volatile("s_waitcnt vmcnt(0)" ::: "memory");
    }
    if(last){
      #pragma unroll
      for(int fi = 0; fi < 2; fi++){
        if(!keep0) afr[fi][0] = bf16x8{};
        if(!keep1) afr[fi][1] = bf16x8{};
      }
    }
    __builtin_amdgcn_s_barrier();
    asm volatile("s_waitcnt lgkmcnt(0)" ::: "memory");
    __builtin_amdgcn_s_setprio(1);
    #pragma unroll
    for(int kk = 0; kk < 2; kk++)
      #pragma unroll
      for(int fi = 0; fi < 2; fi++)
        #pragma unroll
        for(int fj = 0; fj < 3; fj++)
          acc[fi + 4][fj] = mfma_bf16(afr[fi][kk], bfr[fj][kk], acc[fi + 4][fj]);
    __builtin_amdgcn_s_setprio(0);
    __builtin_amdgcn_s_barrier();

    st = st + 1 >= 3 ? 0 : st + 1;
  }

  #pragma unroll
  for(int fi = 0; fi < 6; fi++)
    #pragma unroll
    for(int fj = 0; fj < 3; fj++){
      int m = m0 + wm*96 + fi*16 + lg*4;
      int n = n0 + wn*48 + fj*16 + lo;
      epi(m, n, acc[fi][fj]);
    }
}

// ============ 256x256 tile, BK=64, 8 waves, dbuf-2 (128KB), 4-phase counted-vmcnt ============
// Requires K % 64 == 0, nk >= 2. (round-8/10, proven; used where grid packs to 256)
template<class Epi>
__device__ __forceinline__ void gemm256(const unsigned short* __restrict__ A, int lda, int Amax,
                                        const unsigned short* __restrict__ B, int ldb, int Bmax,
                                        int K, int m0, int n0, Epi epi){
  __shared__ char lds[131072];
  char* ldsA = lds;
  char* ldsB = lds + 65536;
  const int tid = threadIdx.x;
  const int w = tid >> 6, l = tid & 63;
  const int lg = l >> 4, lo = l & 15;
  const int wm = w >> 2, wn = w & 3;

  const int gcol = ((tid & 7) ^ ((tid >> 3) & 7)) * 16;
  const char* gA[2][2]; const char* gB[2][2];
  #pragma unroll
  for(int u = 0; u < 2; u++)
    #pragma unroll
    for(int j = 0; j < 2; j++){
      int ar = m0 + u*128 + j*64 + (tid >> 3); ar = ar < Amax ? ar : Amax - 1;
      gA[u][j] = (const char*)A + (size_t)ar*lda*2 + gcol;
      int br = n0 + u*128 + j*64 + (tid >> 3); br = br < Bmax ? br : Bmax - 1;
      gB[u][j] = (const char*)B + (size_t)br*ldb*2 + gcol;
    }
  auto stageA = [&](int kt, int s, int u){
    size_t koff = (size_t)kt * 128;
    #pragma unroll
    for(int j = 0; j < 2; j++)
      gload_lds16(gA[u][j] + koff, ldsA + s*32768 + u*16384 + j*8192 + tid*16);
  };
  auto stageB = [&](int kt, int s, int u){
    size_t koff = (size_t)kt * 128;
    #pragma unroll
    for(int j = 0; j < 2; j++)
      gload_lds16(gB[u][j] + koff, ldsB + s*32768 + u*16384 + j*8192 + tid*16);
  };

  f32x4 acc[2][4][4] = {};
  const int sw = (lo & 7) << 4;
  const int nk = K >> 6;

  stageB(0, 0, 0); stageB(0, 0, 1); stageA(0, 0, 0); stageA(0, 0, 1);
  asm volatile("s_waitcnt vmcnt(2)" ::: "memory");
  __builtin_amdgcn_s_barrier();

  for(int t = 0; t < nk; t++){
    const int s = t & 1, sn = s ^ 1;
    const bool pf = (t + 1 < nk);
    const char* Ab = ldsA + s*32768;
    const char* Bb = ldsB + s*32768;
    bf16x8 b0[4], b1[4], ar[4];

    #pragma unroll
    for(int fj = 0; fj < 4; fj++)
      b0[fj] = *(const bf16x8*)(Bb + (wn*64 + fj*16 + lo)*128 + ((lg*16) ^ sw));
    #pragma unroll
    for(int fi = 0; fi < 4; fi++)
      ar[fi] = *(const bf16x8*)(Ab + (wm*64 + fi*16 + lo)*128 + ((lg*16) ^ sw));
    if(pf) stageB(t + 1, sn, 0);
    __builtin_amdgcn_s_barrier();
    asm volatile("s_waitcnt lgkmcnt(0)" ::: "memory");
    __builtin_amdgcn_s_setprio(1);
    #pragma unroll
    for(int fi = 0; fi < 4; fi++)
      #pragma unroll
      for(int fj = 0; fj < 4; fj++)
        acc[0][fi][fj] = mfma_bf16(ar[fi], b0[fj], acc[0][fi][fj]);
    __builtin_amdgcn_s_setprio(0);

    #pragma unroll
    for(int fj = 0; fj < 4; fj++)
      b1[fj] = *(const bf16x8*)(Bb + (wn*64 + fj*16 + lo)*128 + ((64 + lg*16) ^ sw));
    #pragma unroll
    for(int fi = 0; fi < 4; fi++)
      ar[fi] = *(const bf16x8*)(Ab + (wm*64 + fi*16 + lo)*128 + ((64 + lg*16) ^ sw));
    if(pf){ stageB(t + 1, sn, 1);
            asm volatile("s_waitcnt vmcnt(4)" ::: "memory"); }
    else  { asm volatile("s_waitcnt vmcnt(0)" ::: "memory"); }
    __builtin_amdgcn_s_barrier();
    asm volatile("s_waitcnt lgkmcnt(0)" ::: "memory");
    __builtin_amdgcn_s_setprio(1);
    #pragma unroll
    for(int fi = 0; fi < 4; fi++)
      #pragma unroll
      for(int fj = 0; fj < 4; fj++)
        acc[0][fi][fj] = mfma_bf16(ar[fi], b1[fj], acc[0][fi][fj]);
    __builtin_amdgcn_s_setprio(0);

    #pragma unroll
    for(int fi = 0; fi < 4; fi++)
      ar[fi] = *(const bf16x8*)(Ab + (128 + wm*64 + fi*16 + lo)*128 + ((lg*16) ^ sw));
    if(pf) stageA(t + 1, sn, 0);
    __builtin_amdgcn_s_barrier();
    asm volatile("s_waitcnt lgkmcnt(0)" ::: "memory");
    __builtin_amdgcn_s_setprio(1);
    #pragma unroll
    for(int fi = 0; fi < 4; fi++)
      #pragma unroll
      for(int fj = 0; fj < 4; fj++)
        acc[1][fi][fj] = mfma_bf16(ar[fi], b0[fj], acc[1][fi][fj]);
    __builtin_amdgcn_s_setprio(0);

    #pragma unroll
    for(int fi = 0; fi < 4; fi++)
      ar[fi] = *(const bf16x8*)(Ab + (128 + wm*64 + fi*16 + lo)*128 + ((64 + lg*16) ^ sw));
    if(pf){ stageA(t + 1, sn, 1);
            asm volatile("s_waitcnt vmcnt(2)" ::: "memory"); }
    __builtin_amdgcn_s_barrier();
    asm volatile("s_waitcnt lgkmcnt(0)" ::: "memory");
    __builtin_amdgcn_s_setprio(1);
    #pragma unroll
    for(int fi = 0; fi < 4; fi++)
      #pragma unroll
      for(int fj = 0; fj < 4; fj++)
        acc[1][fi][fj] = mfma_bf16(ar[fi], b1[fj], acc[1][fi][fj]);
    __builtin_amdgcn_s_setprio(0);
  }

  #pragma unroll
  for(int lh = 0; lh < 2; lh++)
    #pragma unroll
    for(int fi = 0; fi < 4; fi++)
      #pragma unroll
      for(int fj = 0; fj < 4; fj++){
        int m = m0 + lh*128 + wm*64 + fi*16 + lg*4;
        int n = n0 + wn*64 + fj*16 + lo;
        epi(m, n, acc[lh][fi][fj]);
      }
}

// ---------------- projection (gemm384 v3, 240 blocks = perfect 1-round pack) ----------------
__global__ __launch_bounds__(512, 2) void k_proj(const unsigned short* __restrict__ X,
                                                 const unsigned short* __restrict__ Wt,
                                                 unsigned short* __restrict__ Qb,
                                                 unsigned short* __restrict__ Kb,
                                                 unsigned short* __restrict__ Vt){
  int bid = blockIdx.x;                       // 240 blocks, 240 % 8 == 0
  int wg  = (bid & 7) * 30 + (bid >> 3);      // XCD-contiguous chunks
  int m0 = (wg % 10) * 384, n0 = (wg / 10) * 192;
  gemm384(X, DM, MTOK, Wt, DM, 3*DM, DM, m0, n0,
    [=] __device__ (int m, int n, f32x4 v4){
      if(m >= MTOK) return;
      int which = n / DM, r = n % DM, h = r / DH, d = r % DH;
      int b = m / SEQ, s = m % SEQ;
      int bh = b * NHD + h;
      if(which == 2){
        u16x4 o;
        o.x = f2bf(v4.x); o.y = f2bf(v4.y); o.z = f2bf(v4.z); o.w = f2bf(v4.w);
        *(u16x4*)(Vt + ((size_t)bh*DH + d)*SEQ + s) = o;
      } else if(which == 0){
        #pragma unroll
        for(int i = 0; i < 4; i++)
          Qb[((size_t)bh*SEQ + s + i)*DH + d] = f2bf(v4[i] * 0.05103103630798287f);
      } else {
        #pragma unroll
        for(int i = 0; i < 4; i++)
          Kb[((size_t)bh*SEQ + s + i)*DH + d] = f2bf(v4[i]);
      }
    });
}

// ---------------- rel (gemm192): C = Q_all @ E^T, banded epilogue -> relS ----------------
__global__ __launch_bounds__(512) void k_rel(const unsigned short* __restrict__ Qb,
                                             const unsigned short* __restrict__ E,
                                             unsigned short* __restrict__ relS){
  int m0 = blockIdx.x * 192, n0 = blockIdx.y * 192;
  int s0 = m0 % SEQ;
  int qlo = s0, qhi = s0 + 191;
  if(qhi >= SEQ){ qlo = 0; qhi = SEQ - 1; }
  if(n0 + 191 < 919 - qhi || n0 > 1838 - qlo) return;
  gemm192(Qb, DH, NBH*SEQ, E, DH, NREL, DH, m0, n0,
    [=] __device__ (int m, int n, f32x4 v4){
      #pragma unroll
      for(int i = 0; i < 4; i++){
        int mi = m + i;
        if(mi >= NBH*SEQ) continue;
        int q = mi % SEQ;
        int j = n - 919 + q;
        if(j < 0 || j >= SEQ) continue;
        relS[(size_t)mi*SEQ + j] = f2bf(v4[i]);
      }
    });
}

// -------- S-GEMM (gemm256, grid 256): per-bh S = Q K^T; in-place P = exp(S + relS); rowsums --------
__global__ __launch_bounds__(512, 2) void k_sgemm(const unsigned short* __restrict__ Qb,
                                                  const unsigned short* __restrict__ Kb,
                                                  unsigned short* __restrict__ P,
                                                  float* __restrict__ rs2){
  __shared__ float rsLds[256];
  if(threadIdx.x < 256) rsLds[threadIdx.x] = 0.f;
  int bid = blockIdx.x;
  int wg = (bid & 7) * 32 + (bid >> 3);
  int bh = wg >> 4, r = wg & 15;
  int m0 = (r & 3) * 256, n0 = (r >> 2) * 256;
  const unsigned short* A = Qb + (size_t)bh*SEQ*DH;
  const unsigned short* B = Kb + (size_t)bh*SEQ*DH;
  unsigned short* Pbh = P + (size_t)bh*SEQ*SEQ;
  const int lo = threadIdx.x & 15;
  gemm256(A, DH, SEQ, B, DH, SEQ, DH, m0, n0,
    [=] __device__ (int m, int n, f32x4 v4){
      float s[4];
      #pragma unroll
      for(int i = 0; i < 4; i++){
        int mi = m + i;
        float p = 0.f;
        if(mi < SEQ && n < SEQ){
          size_t off = (size_t)mi*SEQ + n;
          p = __expf(v4[i] + bf2f(Pbh[off]));   // same-thread read-then-write: no race
          Pbh[off] = f2bf(p);
        }
        s[i] = p;
      }
      #pragma unroll
      for(int i = 0; i < 4; i++){
        float v = s[i];
        v += __shfl_xor(v, 1); v += __shfl_xor(v, 2);
        v += __shfl_xor(v, 4); v += __shfl_xor(v, 8);
        if(lo == 0) atomicAdd(&rsLds[m - m0 + i], v);
      }
    });
  __syncthreads();
  if(threadIdx.x < 256){
    int row = m0 + threadIdx.x;
    if(row < SEQ) rs2[(((size_t)(n0 >> 8))*NBH + bh)*SEQ + row] = rsLds[threadIdx.x];
  }
}

// -------- PV (gemm192): per-bh ctx = P V (K=920, tail-masked), scale by 1/rowsum -> out --------
__global__ __launch_bounds__(512) void k_pv(const unsigned short* __restrict__ P,
                                            const unsigned short* __restrict__ Vt,
                                            const float* __restrict__ rs2,
                                            float* __restrict__ out){
  int bid = blockIdx.x;                        // 160 blocks
  int idp = (bid & 7) * 20 + (bid >> 3);       // 2 bh per XCD
  int bh = idp / 10, r = idp % 10;
  int m0 = (r % 5) * 192, n0 = (r / 5) * 192;
  const unsigned short* A = P  + (size_t)bh*SEQ*SEQ;
  const unsigned short* B = Vt + (size_t)bh*DH*SEQ;
  const int b = bh >> 2, h = bh & 3;
  gemm192(A, SEQ, SEQ, B, SEQ, DH, SEQ, m0, n0,
    [=] __device__ (int m, int n, f32x4 v4){
      #pragma unroll
      for(int i = 0; i < 4; i++){
        int mi = m + i;
        if(mi >= SEQ) continue;
        float den = rs2[(size_t)bh*SEQ + mi]
                  + rs2[((size_t)1*NBH + bh)*SEQ + mi]
                  + rs2[((size_t)2*NBH + bh)*SEQ + mi]
                  + rs2[((size_t)3*NBH + bh)*SEQ + mi];
        out[((size_t)(b*SEQ + mi))*DM + h*DH + n] = v4[i] / den;
      }
    });
}

extern "C" void kernel_launch(void* const* d_in, const int* in_sizes, int n_in,
                              void* d_out, int out_size, void* d_ws, size_t ws_size,
                              hipStream_t stream){
  const float* X  = (const float*)d_in[0];
  const float* qw = (const float*)d_in[1];
  const float* kw = (const float*)d_in[2];
  const float* vw = (const float*)d_in[3];
  const float* de = (const float*)d_in[4];
  float* out = (float*)d_out;
  char* ws = (char*)d_ws;

  // ws layout (bytes), total 62,412,032:
  // [0, 11304960)           Qb  bf16 (bh,s,d)
  // [11304960, 22609920)    Kb  bf16 (bh,s,d)
  // [22609920, 33914880)    Vt  bf16 (bh,d,s)
  // [33914880, 60999680)    relS bf16 [14720][920]  (== P in place after k_sgemm)
  //                         (aliased before k_rel: Xb at 33914880, Wt at 45219840)
  // [60999680, 62412032)    Eb  bf16 (1839x384); dead after k_rel -> rs2 f32[4][16][920] (235KB)
  unsigned short* Qb   = (unsigned short*)ws;
  unsigned short* Kb   = (unsigned short*)(ws + 11304960);
  unsigned short* Vt   = (unsigned short*)(ws + 22609920);
  unsigned short* relS = (unsigned short*)(ws + 33914880);
  unsigned short* Eb   = (unsigned short*)(ws + 60999680);
  unsigned short* Xb   = (unsigned short*)(ws + 33914880);
  unsigned short* Wt   = (unsigned short*)(ws + 45219840);
  float*          rs2  = (float*)(ws + 60999680);   // aliases Eb (dead after k_rel)

  k_prep<<<dim3(9650), dim3(256), 0, stream>>>(X, de, qw, kw, vw, Xb, Eb, Wt);
  k_proj<<<dim3(240), dim3(512), 0, stream>>>(Xb, Wt, Qb, Kb, Vt);
  k_rel<<<dim3(77,10), dim3(512), 0, stream>>>(Qb, Eb, relS);     // overwrites Xb/Wt (dead)
  k_sgemm<<<dim3(256), dim3(512), 0, stream>>>(Qb, Kb, relS, rs2);// relS -> P; rowsums -> rs2
  k_pv<<<dim3(160), dim3(512), 0, stream>>>(relS, Vt, rs2, out);
}

// Round 14
// 203.931 us; speedup vs baseline: 1.0323x; 1.0323x over previous
//
#include <hip/hip_runtime.h>
#include <cstdint>
#include <cstddef>

// ---- problem constants ----
#define SEQ   920
#define DM    1536
#define DH    384
#define NHD   4
#define NB    4
#define NBH   16          // NB*NHD
#define MTOK  3680        // NB*SEQ
#define NREL  1839        // 2*920-1

typedef short          bf16x8 __attribute__((ext_vector_type(8)));
typedef float          f32x4  __attribute__((ext_vector_type(4)));
typedef unsigned short u16x4  __attribute__((ext_vector_type(4)));
typedef unsigned short u16x8  __attribute__((ext_vector_type(8)));

__device__ __forceinline__ unsigned short f2bf(float f){
  union{float f; unsigned u;} v; v.f = f;
  unsigned r = v.u + 0x7FFFu + ((v.u >> 16) & 1u);
  return (unsigned short)(r >> 16);
}
__device__ __forceinline__ float bf2f(unsigned short h){
  union{unsigned u; float f;} v; v.u = ((unsigned)h) << 16;
  return v.f;
}
__device__ __forceinline__ f32x4 mfma_bf16(bf16x8 a, bf16x8 b, f32x4 c){
  return __builtin_amdgcn_mfma_f32_16x16x32_bf16(a, b, c, 0, 0, 0);
}
__device__ __forceinline__ void gload_lds16(const void* g, void* l){
  __builtin_amdgcn_global_load_lds((const __attribute__((address_space(1))) void*)g,
                                   (__attribute__((address_space(3))) void*)l, 16, 0, 0);
}

// ---- unified prep: weight transpose+convert (blocks 0..6911), X conv (..8959), E conv (..9649) ----
__global__ __launch_bounds__(256) void k_prep(const float* __restrict__ X,
                                              const float* __restrict__ de,
                                              const float* __restrict__ qw,
                                              const float* __restrict__ kw,
                                              const float* __restrict__ vw,
                                              unsigned short* __restrict__ Xb,
                                              unsigned short* __restrict__ Eb,
                                              unsigned short* __restrict__ Wt){
  __shared__ float t[32][33];
  int bid = blockIdx.x;
  if(bid < 6912){
    int z = bid / 2304, rem = bid % 2304;
    int k0 = (rem % 48) * 32, n0 = (rem / 48) * 32;
    const float* w = z == 0 ? qw : (z == 1 ? kw : vw);
    int tx = threadIdx.x & 31, ty = threadIdx.x >> 5;    // (32,8)
    #pragma unroll
    for(int j = 0; j < 4; j++)
      t[ty*4+j][tx] = w[(size_t)(k0 + ty*4 + j) * DM + n0 + tx];
    __syncthreads();
    #pragma unroll
    for(int j = 0; j < 4; j++)
      Wt[(size_t)(z*DM + n0 + ty*4 + j) * DM + k0 + tx] = f2bf(t[tx][ty*4+j]);
  } else if(bid < 6912 + 2048){
    int i = ((bid - 6912) * 256 + threadIdx.x) * 4;
    const int n = MTOK*DM, stride = 2048 * 256 * 4;
    for(; i + 3 < n; i += stride){
      f32x4 v = *(const f32x4*)(X + i);
      u16x4 o; o.x = f2bf(v.x); o.y = f2bf(v.y); o.z = f2bf(v.z); o.w = f2bf(v.w);
      *(u16x4*)(Xb + i) = o;
    }
  } else {
    int i = ((bid - 6912 - 2048) * 256 + threadIdx.x) * 4;
    if(i + 3 < NREL*DH){
      f32x4 v = *(const f32x4*)(de + i);
      u16x4 o; o.x = f2bf(v.x); o.y = f2bf(v.y); o.z = f2bf(v.z); o.w = f2bf(v.w);
      *(u16x4*)(Eb + i) = o;
    }
  }
}

// ====== 384x192 tile, BK=64, 8 waves (4M x 2N, wave 96x96), dbuf-2 (144KB) — v2 (round-12 best) ======
// ONE barrier + one vmcnt(0) per K-step; no intra-iteration barriers: ds_reads are plain IR
// loads so the compiler emits counted lgkmcnt per MFMA cluster, and waves drift within the
// iteration (one wave's MFMA overlaps another's LDS reads).
template<class Epi>
__device__ __forceinline__ void gemm384(const unsigned short* __restrict__ A, int lda, int Amax,
                                        const unsigned short* __restrict__ B, int ldb, int Bmax,
                                        int K, int m0, int n0, Epi epi){
  __shared__ char lds[147456];                 // A dbuf 2x48KB @0, B dbuf 2x24KB @98304
  char* ldsA = lds;
  char* ldsB = lds + 98304;
  const int tid = threadIdx.x;
  const int w = tid >> 6, l = tid & 63;
  const int lg = l >> 4, lo = l & 15;
  const int wm = w >> 1, wn = w & 1;           // wave grid 4(M) x 2(N)

  const int gcol = ((tid & 7) ^ ((tid >> 3) & 7)) * 16;   // pre-swizzled column slot
  const char* gA[6]; const char* gB[3];
  #pragma unroll
  for(int u = 0; u < 6; u++){
    int ar = m0 + u*64 + (tid >> 3); ar = ar < Amax ? ar : Amax - 1;
    gA[u] = (const char*)A + (size_t)ar*lda*2 + gcol;
  }
  #pragma unroll
  for(int v = 0; v < 3; v++){
    int br = n0 + v*64 + (tid >> 3); br = br < Bmax ? br : Bmax - 1;
    gB[v] = (const char*)B + (size_t)br*ldb*2 + gcol;
  }
  auto stage_all = [&](int kt, int s){
    size_t koff = (size_t)kt * 128;
    #pragma unroll
    for(int u = 0; u < 6; u++)
      gload_lds16(gA[u] + koff, ldsA + s*49152 + u*8192 + tid*16);
    #pragma unroll
    for(int v = 0; v < 3; v++)
      gload_lds16(gB[v] + koff, ldsB + s*24576 + v*8192 + tid*16);
  };

  f32x4 acc[6][6] = {};
  const int sw = (lo & 7) << 4;
  const int nk = K >> 6;

  stage_all(0, 0);
  asm volatile("s_waitcnt vmcnt(0)" ::: "memory");
  __builtin_amdgcn_s_barrier();

  for(int t = 0; t < nk; t++){
    const int s = t & 1, sn = s ^ 1;
    const bool pf = (t + 1 < nk);
    const char* Ab = ldsA + s*49152;
    const char* Bb = ldsB + s*24576;
    if(pf) stage_all(t + 1, sn);

    bf16x8 b0[6], b1[6], a0[3], a1[3];
    #pragma unroll
    for(int fj = 0; fj < 6; fj++){
      b0[fj] = *(const bf16x8*)(Bb + (wn*96 + fj*16 + lo)*128 + ((lg*16) ^ sw));
      b1[fj] = *(const bf16x8*)(Bb + (wn*96 + fj*16 + lo)*128 + ((64 + lg*16) ^ sw));
    }
    #pragma unroll
    for(int fi = 0; fi < 3; fi++){
      a0[fi] = *(const bf16x8*)(Ab + (wm*96 + fi*16 + lo)*128 + ((lg*16) ^ sw));
      a1[fi] = *(const bf16x8*)(Ab + (wm*96 + fi*16 + lo)*128 + ((64 + lg*16) ^ sw));
    }
    __builtin_amdgcn_s_setprio(1);
    #pragma unroll
    for(int fi = 0; fi < 3; fi++)
      #pragma unroll
      for(int fj = 0; fj < 6; fj++)
        acc[fi][fj] = mfma_bf16(a0[fi], b0[fj], acc[fi][fj]);
    #pragma unroll
    for(int fi = 0; fi < 3; fi++)
      #pragma unroll
      for(int fj = 0; fj < 6; fj++)
        acc[fi][fj] = mfma_bf16(a1[fi], b1[fj], acc[fi][fj]);
    __builtin_amdgcn_s_setprio(0);

    #pragma unroll
    for(int fi = 0; fi < 3; fi++){
      a0[fi] = *(const bf16x8*)(Ab + (wm*96 + (fi+3)*16 + lo)*128 + ((lg*16) ^ sw));
      a1[fi] = *(const bf16x8*)(Ab + (wm*96 + (fi+3)*16 + lo)*128 + ((64 + lg*16) ^ sw));
    }
    __builtin_amdgcn_s_setprio(1);
    #pragma unroll
    for(int fi = 0; fi < 3; fi++)
      #pragma unroll
      for(int fj = 0; fj < 6; fj++)
        acc[fi+3][fj] = mfma_bf16(a0[fi], b0[fj], acc[fi+3][fj]);
    #pragma unroll
    for(int fi = 0; fi < 3; fi++)
      #pragma unroll
      for(int fj = 0; fj < 6; fj++)
        acc[fi+3][fj] = mfma_bf16(a1[fi], b1[fj], acc[fi+3][fj]);
    __builtin_amdgcn_s_setprio(0);

    if(pf){
      asm volatile("s_waitcnt vmcnt(0)" ::: "memory");   // tile t+1 landed
      __builtin_amdgcn_s_barrier();
    }
  }

  #pragma unroll
  for(int fi = 0; fi < 6; fi++)
    #pragma unroll
    for(int fj = 0; fj < 6; fj++){
      int m = m0 + wm*96 + fi*16 + lg*4;
      int n = n0 + wn*96 + fj*16 + lo;
      epi(m, n, acc[fi][fj]);
    }
}

// ====== 192x(64*NF) tile, BK=64, 8-wave, ring-3, counted-vmcnt, 3-PHASE GEMM ======
// NF=3 -> 192x192 (round-6, proven). NF=2 -> 192x128 (same protocol, B-ring 16KB/slot,
// 5 loads/tile, steady vmcnt(5)). Per-wave output 96 x 16*NF.
template<int NF, class Epi>
__device__ __forceinline__ void gemm192(const unsigned short* __restrict__ A, int lda, int Amax,
                                        const unsigned short* __restrict__ B, int ldb, int Bmax,
                                        int K, int m0, int n0, Epi epi){
  __shared__ unsigned short As[3*192*64];
  __shared__ unsigned short Bs[3*64*NF*64];
  const int tid = threadIdx.x;
  const int w = tid >> 6, l = tid & 63;
  const int lg = l >> 4, lo = l & 15;
  const int wm = w >> 2, wn = w & 3;
  const int BSLOT = 8192*NF;                   // bytes per B ring slot

  const char* ga[3]; const char* gb[NF];
  #pragma unroll
  for(int r = 0; r < 3; r++){
    int row = r*64 + (tid >> 3);
    int gslot = (tid & 7) ^ (row & 7);
    int ar = m0 + row; ar = ar < Amax ? ar : Amax - 1;
    ga[r] = (const char*)A + (size_t)ar*lda*2 + gslot*16;
  }
  #pragma unroll
  for(int r = 0; r < NF; r++){
    int row = r*64 + (tid >> 3);
    int gslot = (tid & 7) ^ (row & 7);
    int br = n0 + row; br = br < Bmax ? br : Bmax - 1;
    gb[r] = (const char*)B + (size_t)br*ldb*2 + gslot*16;
  }
  const int ldst = tid * 16;

  auto stage_pair = [&](int kt, int slot, int r){
    size_t koff = (size_t)kt * 128;
    gload_lds16(ga[r] + koff, (char*)As + slot*24576 + r*8192 + ldst);
    if(r < NF)
      gload_lds16(gb[r] + koff, (char*)Bs + slot*BSLOT + r*8192 + ldst);
  };
  auto wait_steady = [&]{
    if constexpr(NF == 3) asm volatile("s_waitcnt vmcnt(6)" ::: "memory");
    else                  asm volatile("s_waitcnt vmcnt(5)" ::: "memory");
  };

  f32x4 acc[6][NF] = {};
  const int sw = (lo & 7) << 4;
  const int nk = (2*K + 127) >> 7;
  const int tb = 2*K - (nk - 1)*128;
  const bool keep0 = (lg*16) < tb;
  const bool keep1 = (64 + lg*16) < tb;

  #pragma unroll
  for(int r = 0; r < 3; r++) stage_pair(0, 0, r);
  #pragma unroll
  for(int r = 0; r < 3; r++) stage_pair(1, 1, r);
  wait_steady();
  __builtin_amdgcn_s_barrier();

  int st = 0;
  for(int t = 0; t < nk; t++){
    const bool last = (t == nk - 1);
    const bool pf = (t + 2 < nk);
    const int s2 = st + 2 >= 3 ? st - 1 : st + 2;
    const char* Ab = (const char*)As + st*24576;
    const char* Bb = (const char*)Bs + st*BSLOT;

    bf16x8 bfr[NF][2], afr[2][2];

    #pragma unroll
    for(int fj = 0; fj < NF; fj++){
      int row = wn*(16*NF) + fj*16 + lo;
      #pragma unroll
      for(int kk = 0; kk < 2; kk++)
        bfr[fj][kk] = *(const bf16x8*)(Bb + row*128 + ((kk*64 + lg*16) ^ sw));
    }
    #pragma unroll
    for(int fi = 0; fi < 2; fi++){
      int row = wm*96 + fi*16 + lo;
      #pragma unroll
      for(int kk = 0; kk < 2; kk++)
        afr[fi][kk] = *(const bf16x8*)(Ab + row*128 + ((kk*64 + lg*16) ^ sw));
    }
    if(pf) stage_pair(t + 2, s2, 0);
    if(last){
      #pragma unroll
      for(int fi = 0; fi < 2; fi++){
        if(!keep0) afr[fi][0] = bf16x8{};
        if(!keep1) afr[fi][1] = bf16x8{};
      }
    }
    __builtin_amdgcn_s_barrier();
    asm volatile("s_waitcnt lgkmcnt(0)" ::: "memory");
    __builtin_amdgcn_s_setprio(1);
    #pragma unroll
    for(int kk = 0; kk < 2; kk++)
      #pragma unroll
      for(int fi = 0; fi < 2; fi++)
        #pragma unroll
        for(int fj = 0; fj < NF; fj++)
          acc[fi][fj] = mfma_bf16(afr[fi][kk], bfr[fj][kk], acc[fi][fj]);
    __builtin_amdgcn_s_setprio(0);
    __builtin_amdgcn_s_barrier();

    #pragma unroll
    for(int fi = 0; fi < 2; fi++){
      int row = wm*96 + (fi + 2)*16 + lo;
      #pragma unroll
      for(int kk = 0; kk < 2; kk++)
        afr[fi][kk] = *(const bf16x8*)(Ab + row*128 + ((kk*64 + lg*16) ^ sw));
    }
    if(pf) stage_pair(t + 2, s2, 1);
    if(last){
      #pragma unroll
      for(int fi = 0; fi < 2; fi++){
        if(!keep0) afr[fi][0] = bf16x8{};
        if(!keep1) afr[fi][1] = bf16x8{};
      }
    }
    __builtin_amdgcn_s_barrier();
    asm volatile("s_waitcnt lgkmcnt(0)" ::: "memory");
    __builtin_amdgcn_s_setprio(1);
    #pragma unroll
    for(int kk = 0; kk < 2; kk++)
      #pragma unroll
      for(int fi = 0; fi < 2; fi++)
        #pragma unroll
        for(int fj = 0; fj < NF; fj++)
          acc[fi + 2][fj] = mfma_bf16(afr[fi][kk], bfr[fj][kk], acc[fi + 2][fj]);
    __builtin_amdgcn_s_setprio(0);
    __builtin_amdgcn_s_barrier();

    #pragma unroll
    for(int fi = 0; fi < 2; fi++){
      int row = wm*96 + (fi + 4)*16 + lo;
      #pragma unroll
      for(int kk = 0; kk < 2; kk++)
        afr[fi][kk] = *(const bf16x8*)(Ab + row*128 + ((kk*64 + lg*16) ^ sw));
    }
    if(pf){
      stage_pair(t + 2, s2, 2);
      wait_steady();
    } else if(t + 1 < nk){
      asm volatile("s_waitcnt vmcnt(0)" ::: "memory");
    }
    if(last){
      #pragma unroll
      for(int fi = 0; fi < 2; fi++){
        if(!keep0) afr[fi][0] = bf16x8{};
        if(!keep1) afr[fi][1] = bf16x8{};
      }
    }
    __builtin_amdgcn_s_barrier();
    asm volatile("s_waitcnt lgkmcnt(0)" ::: "memory");
    __builtin_amdgcn_s_setprio(1);
    #pragma unroll
    for(int kk = 0; kk < 2; kk++)
      #pragma unroll
      for(int fi = 0; fi < 2; fi++)
        #pragma unroll
        for(int fj = 0; fj < NF; fj++)
          acc[fi + 4][fj] = mfma_bf16(afr[fi][kk], bfr[fj][kk], acc[fi + 4][fj]);
    __builtin_amdgcn_s_setprio(0);
    __builtin_amdgcn_s_barrier();

    st = st + 1 >= 3 ? 0 : st + 1;
  }

  #pragma unroll
  for(int fi = 0; fi < 6; fi++)
    #pragma unroll
    for(int fj = 0; fj < NF; fj++){
      int m = m0 + wm*96 + fi*16 + lg*4;
      int n = n0 + wn*(16*NF) + fj*16 + lo;
      epi(m, n, acc[fi][fj]);
    }
}

// ============ 256x256 tile, BK=64, 8 waves, dbuf-2 (128KB), 4-phase counted-vmcnt ============
// Requires K % 64 == 0, nk >= 2. (round-8/10, proven; used where grid packs to 256)
template<class Epi>
__device__ __forceinline__ void gemm256(const unsigned short* __restrict__ A, int lda, int Amax,
                                        const unsigned short* __restrict__ B, int ldb, int Bmax,
                                        int K, int m0, int n0, Epi epi){
  __shared__ char lds[131072];
  char* ldsA = lds;
  char* ldsB = lds + 65536;
  const int tid = threadIdx.x;
  const int w = tid >> 6, l = tid & 63;
  const int lg = l >> 4, lo = l & 15;
  const int wm = w >> 2, wn = w & 3;

  const int gcol = ((tid & 7) ^ ((tid >> 3) & 7)) * 16;
  const char* gA[2][2]; const char* gB[2][2];
  #pragma unroll
  for(int u = 0; u < 2; u++)
    #pragma unroll
    for(int j = 0; j < 2; j++){
      int ar = m0 + u*128 + j*64 + (tid >> 3); ar = ar < Amax ? ar : Amax - 1;
      gA[u][j] = (const char*)A + (size_t)ar*lda*2 + gcol;
      int br = n0 + u*128 + j*64 + (tid >> 3); br = br < Bmax ? br : Bmax - 1;
      gB[u][j] = (const char*)B + (size_t)br*ldb*2 + gcol;
    }
  auto stageA = [&](int kt, int s, int u){
    size_t koff = (size_t)kt * 128;
    #pragma unroll
    for(int j = 0; j < 2; j++)
      gload_lds16(gA[u][j] + koff, ldsA + s*32768 + u*16384 + j*8192 + tid*16);
  };
  auto stageB = [&](int kt, int s, int u){
    size_t koff = (size_t)kt * 128;
    #pragma unroll
    for(int j = 0; j < 2; j++)
      gload_lds16(gB[u][j] + koff, ldsB + s*32768 + u*16384 + j*8192 + tid*16);
  };

  f32x4 acc[2][4][4] = {};
  const int sw = (lo & 7) << 4;
  const int nk = K >> 6;

  stageB(0, 0, 0); stageB(0, 0, 1); stageA(0, 0, 0); stageA(0, 0, 1);
  asm volatile("s_waitcnt vmcnt(2)" ::: "memory");
  __builtin_amdgcn_s_barrier();

  for(int t = 0; t < nk; t++){
    const int s = t & 1, sn = s ^ 1;
    const bool pf = (t + 1 < nk);
    const char* Ab = ldsA + s*32768;
    const char* Bb = ldsB + s*32768;
    bf16x8 b0[4], b1[4], ar[4];

    #pragma unroll
    for(int fj = 0; fj < 4; fj++)
      b0[fj] = *(const bf16x8*)(Bb + (wn*64 + fj*16 + lo)*128 + ((lg*16) ^ sw));
    #pragma unroll
    for(int fi = 0; fi < 4; fi++)
      ar[fi] = *(const bf16x8*)(Ab + (wm*64 + fi*16 + lo)*128 + ((lg*16) ^ sw));
    if(pf) stageB(t + 1, sn, 0);
    __builtin_amdgcn_s_barrier();
    asm volatile("s_waitcnt lgkmcnt(0)" ::: "memory");
    __builtin_amdgcn_s_setprio(1);
    #pragma unroll
    for(int fi = 0; fi < 4; fi++)
      #pragma unroll
      for(int fj = 0; fj < 4; fj++)
        acc[0][fi][fj] = mfma_bf16(ar[fi], b0[fj], acc[0][fi][fj]);
    __builtin_amdgcn_s_setprio(0);

    #pragma unroll
    for(int fj = 0; fj < 4; fj++)
      b1[fj] = *(const bf16x8*)(Bb + (wn*64 + fj*16 + lo)*128 + ((64 + lg*16) ^ sw));
    #pragma unroll
    for(int fi = 0; fi < 4; fi++)
      ar[fi] = *(const bf16x8*)(Ab + (wm*64 + fi*16 + lo)*128 + ((64 + lg*16) ^ sw));
    if(pf){ stageB(t + 1, sn, 1);
            asm volatile("s_waitcnt vmcnt(4)" ::: "memory"); }
    else  { asm volatile("s_waitcnt vmcnt(0)" ::: "memory"); }
    __builtin_amdgcn_s_barrier();
    asm volatile("s_waitcnt lgkmcnt(0)" ::: "memory");
    __builtin_amdgcn_s_setprio(1);
    #pragma unroll
    for(int fi = 0; fi < 4; fi++)
      #pragma unroll
      for(int fj = 0; fj < 4; fj++)
        acc[0][fi][fj] = mfma_bf16(ar[fi], b1[fj], acc[0][fi][fj]);
    __builtin_amdgcn_s_setprio(0);

    #pragma unroll
    for(int fi = 0; fi < 4; fi++)
      ar[fi] = *(const bf16x8*)(Ab + (128 + wm*64 + fi*16 + lo)*128 + ((lg*16) ^ sw));
    if(pf) stageA(t + 1, sn, 0);
    __builtin_amdgcn_s_barrier();
    asm volatile("s_waitcnt lgkmcnt(0)" ::: "memory");
    __builtin_amdgcn_s_setprio(1);
    #pragma unroll
    for(int fi = 0; fi < 4; fi++)
      #pragma unroll
      for(int fj = 0; fj < 4; fj++)
        acc[1][fi][fj] = mfma_bf16(ar[fi], b0[fj], acc[1][fi][fj]);
    __builtin_amdgcn_s_setprio(0);

    #pragma unroll
    for(int fi = 0; fi < 4; fi++)
      ar[fi] = *(const bf16x8*)(Ab + (128 + wm*64 + fi*16 + lo)*128 + ((64 + lg*16) ^ sw));
    if(pf){ stageA(t + 1, sn, 1);
            asm volatile("s_waitcnt vmcnt(2)" ::: "memory"); }
    __builtin_amdgcn_s_barrier();
    asm volatile("s_waitcnt lgkmcnt(0)" ::: "memory");
    __builtin_amdgcn_s_setprio(1);
    #pragma unroll
    for(int fi = 0; fi < 4; fi++)
      #pragma unroll
      for(int fj = 0; fj < 4; fj++)
        acc[1][fi][fj] = mfma_bf16(ar[fi], b1[fj], acc[1][fi][fj]);
    __builtin_amdgcn_s_setprio(0);
  }

  #pragma unroll
  for(int lh = 0; lh < 2; lh++)
    #pragma unroll
    for(int fi = 0; fi < 4; fi++)
      #pragma unroll
      for(int fj = 0; fj < 4; fj++){
        int m = m0 + lh*128 + wm*64 + fi*16 + lg*4;
        int n = n0 + wn*64 + fj*16 + lo;
        epi(m, n, acc[lh][fi][fj]);
      }
}

// ---------------- projection (gemm384 v2, 240 blocks = perfect 1-round pack) ----------------
__global__ __launch_bounds__(512, 2) void k_proj(const unsigned short* __restrict__ X,
                                                 const unsigned short* __restrict__ Wt,
                                                 unsigned short* __restrict__ Qb,
                                                 unsigned short* __restrict__ Kb,
                                                 unsigned short* __restrict__ Vt){
  int bid = blockIdx.x;                       // 240 blocks, 240 % 8 == 0
  int wg  = (bid & 7) * 30 + (bid >> 3);      // XCD-contiguous chunks
  int m0 = (wg % 10) * 384, n0 = (wg / 10) * 192;
  gemm384(X, DM, MTOK, Wt, DM, 3*DM, DM, m0, n0,
    [=] __device__ (int m, int n, f32x4 v4){
      if(m >= MTOK) return;
      int which = n / DM, r = n % DM, h = r / DH, d = r % DH;
      int b = m / SEQ, s = m % SEQ;
      int bh = b * NHD + h;
      if(which == 2){
        u16x4 o;
        o.x = f2bf(v4.x); o.y = f2bf(v4.y); o.z = f2bf(v4.z); o.w = f2bf(v4.w);
        *(u16x4*)(Vt + ((size_t)bh*DH + d)*SEQ + s) = o;
      } else if(which == 0){
        #pragma unroll
        for(int i = 0; i < 4; i++)
          Qb[((size_t)bh*SEQ + s + i)*DH + d] = f2bf(v4[i] * 0.05103103630798287f);
      } else {
        #pragma unroll
        for(int i = 0; i < 4; i++)
          Kb[((size_t)bh*SEQ + s + i)*DH + d] = f2bf(v4[i]);
      }
    });
}

// ---------------- rel (gemm192<3>): C = Q_all @ E^T, banded epilogue -> relS ----------------
__global__ __launch_bounds__(512) void k_rel(const unsigned short* __restrict__ Qb,
                                             const unsigned short* __restrict__ E,
                                             unsigned short* __restrict__ relS){
  int m0 = blockIdx.x * 192, n0 = blockIdx.y * 192;
  int s0 = m0 % SEQ;
  int qlo = s0, qhi = s0 + 191;
  if(qhi >= SEQ){ qlo = 0; qhi = SEQ - 1; }
  if(n0 + 191 < 919 - qhi || n0 > 1838 - qlo) return;
  gemm192<3>(Qb, DH, NBH*SEQ, E, DH, NREL, DH, m0, n0,
    [=] __device__ (int m, int n, f32x4 v4){
      #pragma unroll
      for(int i = 0; i < 4; i++){
        int mi = m + i;
        if(mi >= NBH*SEQ) continue;
        int q = mi % SEQ;
        int j = n - 919 + q;
        if(j < 0 || j >= SEQ) continue;
        relS[(size_t)mi*SEQ + j] = f2bf(v4[i]);
      }
    });
}

// -------- S-GEMM (gemm256, grid 256): per-bh S = Q K^T; in-place P = exp(S + relS); rowsums --------
__global__ __launch_bounds__(512, 2) void k_sgemm(const unsigned short* __restrict__ Qb,
                                                  const unsigned short* __restrict__ Kb,
                                                  unsigned short* __restrict__ P,
                                                  float* __restrict__ rs2){
  __shared__ float rsLds[256];
  if(threadIdx.x < 256) rsLds[threadIdx.x] = 0.f;
  int bid = blockIdx.x;
  int wg = (bid & 7) * 32 + (bid >> 3);
  int bh = wg >> 4, r = wg & 15;
  int m0 = (r & 3) * 256, n0 = (r >> 2) * 256;
  const unsigned short* A = Qb + (size_t)bh*SEQ*DH;
  const unsigned short* B = Kb + (size_t)bh*SEQ*DH;
  unsigned short* Pbh = P + (size_t)bh*SEQ*SEQ;
  const int lo = threadIdx.x & 15;
  gemm256(A, DH, SEQ, B, DH, SEQ, DH, m0, n0,
    [=] __device__ (int m, int n, f32x4 v4){
      float s[4];
      #pragma unroll
      for(int i = 0; i < 4; i++){
        int mi = m + i;
        float p = 0.f;
        if(mi < SEQ && n < SEQ){
          size_t off = (size_t)mi*SEQ + n;
          p = __expf(v4[i] + bf2f(Pbh[off]));   // same-thread read-then-write: no race
          Pbh[off] = f2bf(p);
        }
        s[i] = p;
      }
      #pragma unroll
      for(int i = 0; i < 4; i++){
        float v = s[i];
        v += __shfl_xor(v, 1); v += __shfl_xor(v, 2);
        v += __shfl_xor(v, 4); v += __shfl_xor(v, 8);
        if(lo == 0) atomicAdd(&rsLds[m - m0 + i], v);
      }
    });
  __syncthreads();
  if(threadIdx.x < 256){
    int row = m0 + threadIdx.x;
    if(row < SEQ) rs2[(((size_t)(n0 >> 8))*NBH + bh)*SEQ + row] = rsLds[threadIdx.x];
  }
}

// -------- PV (gemm192<2>, 240 blocks = perfect pack): ctx = P V, scale by 1/rowsum -> out --------
__global__ __launch_bounds__(512) void k_pv(const unsigned short* __restrict__ P,
                                            const unsigned short* __restrict__ Vt,
                                            const float* __restrict__ rs2,
                                            float* __restrict__ out){
  int bid = blockIdx.x;                        // 240 blocks, 240 % 8 == 0
  int wg = (bid & 7) * 30 + (bid >> 3);        // XCD-contiguous chunks
  int bh = wg / 15, r = wg % 15;               // per bh: 5 m-tiles (192) x 3 n-tiles (128)
  int m0 = (r % 5) * 192, n0 = (r / 5) * 128;
  const unsigned short* A = P  + (size_t)bh*SEQ*SEQ;
  const unsigned short* B = Vt + (size_t)bh*DH*SEQ;
  const int b = bh >> 2, h = bh & 3;
  gemm192<2>(A, SEQ, SEQ, B, SEQ, DH, SEQ, m0, n0,
    [=] __device__ (int m, int n, f32x4 v4){
      #pragma unroll
      for(int i = 0; i < 4; i++){
        int mi = m + i;
        if(mi >= SEQ) continue;
        float den = rs2[(size_t)bh*SEQ + mi]
                  + rs2[((size_t)1*NBH + bh)*SEQ + mi]
                  + rs2[((size_t)2*NBH + bh)*SEQ + mi]
                  + rs2[((size_t)3*NBH + bh)*SEQ + mi];
        out[((size_t)(b*SEQ + mi))*DM + h*DH + n] = v4[i] / den;
      }
    });
}

extern "C" void kernel_launch(void* const* d_in, const int* in_sizes, int n_in,
                              void* d_out, int out_size, void* d_ws, size_t ws_size,
                              hipStream_t stream){
  const float* X  = (const float*)d_in[0];
  const float* qw = (const float*)d_in[1];
  const float* kw = (const float*)d_in[2];
  const float* vw = (const float*)d_in[3];
  const float* de = (const float*)d_in[4];
  float* out = (float*)d_out;
  char* ws = (char*)d_ws;

  // ws layout (bytes), total 62,412,032:
  // [0, 11304960)           Qb  bf16 (bh,s,d)
  // [11304960, 22609920)    Kb  bf16 (bh,s,d)
  // [22609920, 33914880)    Vt  bf16 (bh,d,s)
  // [33914880, 60999680)    relS bf16 [14720][920]  (== P in place after k_sgemm)
  //                         (aliased before k_rel: Xb at 33914880, Wt at 45219840)
  // [60999680, 62412032)    Eb  bf16 (1839x384); dead after k_rel -> rs2 f32[4][16][920] (235KB)
  unsigned short* Qb   = (unsigned short*)ws;
  unsigned short* Kb   = (unsigned short*)(ws + 11304960);
  unsigned short* Vt   = (unsigned short*)(ws + 22609920);
  unsigned short* relS = (unsigned short*)(ws + 33914880);
  unsigned short* Eb   = (unsigned short*)(ws + 60999680);
  unsigned short* Xb   = (unsigned short*)(ws + 33914880);
  unsigned short* Wt   = (unsigned short*)(ws + 45219840);
  float*          rs2  = (float*)(ws + 60999680);   // aliases Eb (dead after k_rel)

  k_prep<<<dim3(9650), dim3(256), 0, stream>>>(X, de, qw, kw, vw, Xb, Eb, Wt);
  k_proj<<<dim3(240), dim3(512), 0, stream>>>(Xb, Wt, Qb, Kb, Vt);
  k_rel<<<dim3(77,10), dim3(512), 0, stream>>>(Qb, Eb, relS);     // overwrites Xb/Wt (dead)
  k_sgemm<<<dim3(256), dim3(512), 0, stream>>>(Qb, Kb, relS, rs2);// relS -> P; rowsums -> rs2
  k_pv<<<dim3(240), dim3(512), 0, stream>>>(relS, Vt, rs2, out);
}